// Round 1
// baseline (992.036 us; speedup 1.0000x reference)
//
#include <hip/hip_runtime.h>

#define BATCH 32
#define LSEQ  2048
#define DDIM  128
#define QT    64
#define KB    64
#define RSCALE 0.08838834764831845f  // 1/sqrt(128)

typedef __bf16 bf16;
typedef __bf16 bf16x4 __attribute__((ext_vector_type(4)));
typedef __bf16 bf16x8 __attribute__((ext_vector_type(8)));
typedef float  f32x4  __attribute__((ext_vector_type(4)));

// ---------------- prep: fp32 -> bf16 (optionally scaled) ----------------
__global__ void convert_kernel(const float4* __restrict__ src,
                               bf16x4* __restrict__ dst, int n4, float scale) {
    int i = blockIdx.x * blockDim.x + threadIdx.x;
    int stride = gridDim.x * blockDim.x;
    for (; i < n4; i += stride) {
        float4 v = src[i];
        bf16x4 o;
        o[0] = (bf16)(v.x * scale);
        o[1] = (bf16)(v.y * scale);
        o[2] = (bf16)(v.z * scale);
        o[3] = (bf16)(v.w * scale);
        dst[i] = o;
    }
}

// ---------------- prep: V [b][k][d] fp32 -> Vt [b][d][k] bf16 ----------------
__global__ void transpose_v_kernel(const float* __restrict__ V, bf16* __restrict__ Vt) {
    __shared__ float T[64][33];  // +1 pad breaks bank conflicts on column reads
    const int kt = blockIdx.x, dt = blockIdx.y, b = blockIdx.z;
    const int t = threadIdx.x;
#pragma unroll
    for (int i = 0; i < 2; ++i) {
        int flat = t + i * 256;          // 0..511
        int k  = flat >> 3;              // 0..63
        int d4 = (flat & 7) * 4;         // 0..28
        const float4 v = *(const float4*)(V +
            ((size_t)(b * LSEQ + kt * 64 + k) * DDIM + dt * 32 + d4));
        T[k][d4 + 0] = v.x; T[k][d4 + 1] = v.y;
        T[k][d4 + 2] = v.z; T[k][d4 + 3] = v.w;
    }
    __syncthreads();
    int dd  = t >> 3;        // 0..31
    int kk8 = (t & 7) * 8;   // 0..56
    bf16x8 o;
#pragma unroll
    for (int e = 0; e < 8; ++e) o[e] = (bf16)T[kk8 + e][dd];
    *(bf16x8*)(Vt + ((size_t)(b * DDIM + dt * 32 + dd) * LSEQ + kt * 64 + kk8)) = o;
}

// ---------------- main fused attention ----------------
__global__ __launch_bounds__(256, 2)
void attn_kernel(const bf16* __restrict__ Qb, const bf16* __restrict__ Kb,
                 const bf16* __restrict__ Vt,
                 float* __restrict__ Out, float* __restrict__ Attn) {
    __shared__ __attribute__((aligned(16))) bf16 Klds[KB * DDIM];   // swizzled
    __shared__ __attribute__((aligned(16))) bf16 Vtlds[DDIM * KB];  // swizzled
    __shared__ __attribute__((aligned(16))) bf16 Plds[4][16 * KB];  // per-wave, swizzled

    const int qt = blockIdx.x, b = blockIdx.y;
    const int tid = threadIdx.x;
    const int wave = tid >> 6, lane = tid & 63;
    const int g = lane >> 4, li = lane & 15;
    const int qw = qt * QT + wave * 16;  // wave's first q row

    // Q A-fragments (row = li, k-chunk = g*8), 4 chunks over D=128
    bf16x8 qa[4];
    {
        const bf16* qptr = Qb + (size_t)(b * LSEQ + qw + li) * DDIM + g * 8;
#pragma unroll
        for (int c = 0; c < 4; ++c) qa[c] = *(const bf16x8*)(qptr + c * 32);
    }

    float m[4], l[4];
#pragma unroll
    for (int j = 0; j < 4; ++j) { m[j] = -1e30f; l[j] = 0.0f; }

    // ---------- pass 1: row max + sumexp ----------
    for (int kb = 0; kb < LSEQ / KB; ++kb) {
        {
            const bf16* kp = Kb + (size_t)(b * LSEQ + kb * KB) * DDIM;
#pragma unroll
            for (int i = 0; i < 4; ++i) {
                int flat = tid + i * 256;        // 0..1023
                int kr = flat >> 4;              // 0..63
                int c8 = (flat & 15) * 8;        // 0..120
                bf16x8 v = *(const bf16x8*)(kp + kr * DDIM + c8);
                int idx = (kr * DDIM + c8) ^ ((kr & 7) << 3);
                *(bf16x8*)&Klds[idx] = v;
            }
        }
        __syncthreads();
        f32x4 st[4];
#pragma unroll
        for (int kt = 0; kt < 4; ++kt) {
            f32x4 s = {0.f, 0.f, 0.f, 0.f};
            int krow = kt * 16 + li;
#pragma unroll
            for (int c = 0; c < 4; ++c) {
                int idx = (krow * DDIM + c * 32 + g * 8) ^ ((krow & 7) << 3);
                bf16x8 kf = *(const bf16x8*)&Klds[idx];
                s = __builtin_amdgcn_mfma_f32_16x16x32_bf16(qa[c], kf, s, 0, 0, 0);
            }
            st[kt] = s;
        }
#pragma unroll
        for (int j = 0; j < 4; ++j) {
            float sm = fmaxf(fmaxf(st[0][j], st[1][j]), fmaxf(st[2][j], st[3][j]));
            float mn = fmaxf(m[j], sm);
            float acc = l[j] * __expf(m[j] - mn);
#pragma unroll
            for (int kt = 0; kt < 4; ++kt) acc += __expf(st[kt][j] - mn);
            m[j] = mn; l[j] = acc;
        }
        __syncthreads();
    }

    // merge partial stats across the 16 lanes of each group
    float rl[4];
#pragma unroll
    for (int j = 0; j < 4; ++j) {
#pragma unroll
        for (int off = 1; off < 16; off <<= 1) {
            float mo = __shfl_xor(m[j], off);
            float lo = __shfl_xor(l[j], off);
            float mn = fmaxf(m[j], mo);
            l[j] = l[j] * __expf(m[j] - mn) + lo * __expf(mo - mn);
            m[j] = mn;
        }
        rl[j] = 1.0f / l[j];
    }

    // ---------- pass 2: recompute, write attn, accumulate O ----------
    f32x4 o[8];
#pragma unroll
    for (int dt = 0; dt < 8; ++dt) o[dt] = (f32x4){0.f, 0.f, 0.f, 0.f};
    float* attnRowBase = Attn + (size_t)b * LSEQ * LSEQ;

    for (int kb = 0; kb < LSEQ / KB; ++kb) {
        {
            const bf16* kp = Kb + (size_t)(b * LSEQ + kb * KB) * DDIM;
#pragma unroll
            for (int i = 0; i < 4; ++i) {
                int flat = tid + i * 256;
                int kr = flat >> 4;
                int c8 = (flat & 15) * 8;
                bf16x8 v = *(const bf16x8*)(kp + kr * DDIM + c8);
                int idx = (kr * DDIM + c8) ^ ((kr & 7) << 3);
                *(bf16x8*)&Klds[idx] = v;
            }
            const bf16* vp = Vt + (size_t)b * DDIM * LSEQ + kb * KB;
#pragma unroll
            for (int i = 0; i < 4; ++i) {
                int flat = tid + i * 256;
                int dr = flat >> 3;              // 0..127
                int k8 = (flat & 7) * 8;         // 0..56
                bf16x8 v = *(const bf16x8*)(vp + (size_t)dr * LSEQ + k8);
                int idx = (dr * KB + k8) ^ ((dr & 7) << 3);
                *(bf16x8*)&Vtlds[idx] = v;
            }
        }
        __syncthreads();

#pragma unroll
        for (int kt = 0; kt < 4; ++kt) {
            f32x4 s = {0.f, 0.f, 0.f, 0.f};
            int krow = kt * 16 + li;
#pragma unroll
            for (int c = 0; c < 4; ++c) {
                int idx = (krow * DDIM + c * 32 + g * 8) ^ ((krow & 7) << 3);
                bf16x8 kf = *(const bf16x8*)&Klds[idx];
                s = __builtin_amdgcn_mfma_f32_16x16x32_bf16(qa[c], kf, s, 0, 0, 0);
            }
#pragma unroll
            for (int j = 0; j < 4; ++j) {
                float p = __expf(s[j] - m[j]) * rl[j];
                int qrow = g * 4 + j;
                attnRowBase[(size_t)(qw + qrow) * LSEQ + kb * KB + kt * 16 + li] = p;
                int idx = (qrow * KB + kt * 16 + li) ^ ((qrow & 7) << 3);
                Plds[wave][idx] = (bf16)p;
            }
        }

        // PV: A = P (rows q), B = Vt (cols d)
        bf16x8 pa[2];
#pragma unroll
        for (int kk = 0; kk < 2; ++kk) {
            int idx = (li * KB + kk * 32 + g * 8) ^ ((li & 7) << 3);
            pa[kk] = *(const bf16x8*)&Plds[wave][idx];
        }
#pragma unroll
        for (int dt = 0; dt < 8; ++dt) {
#pragma unroll
            for (int kk = 0; kk < 2; ++kk) {
                int dv = dt * 16 + li;
                int idx = (dv * KB + kk * 32 + g * 8) ^ ((dv & 7) << 3);
                bf16x8 vf = *(const bf16x8*)&Vtlds[idx];
                o[dt] = __builtin_amdgcn_mfma_f32_16x16x32_bf16(pa[kk], vf, o[dt], 0, 0, 0);
            }
        }
        __syncthreads();
    }

    // epilogue: O store
#pragma unroll
    for (int dt = 0; dt < 8; ++dt)
#pragma unroll
        for (int j = 0; j < 4; ++j)
            Out[(size_t)(b * LSEQ + qw + g * 4 + j) * DDIM + dt * 16 + li] = o[dt][j];
}

extern "C" void kernel_launch(void* const* d_in, const int* in_sizes, int n_in,
                              void* d_out, int out_size, void* d_ws, size_t ws_size,
                              hipStream_t stream) {
    const float* qu = (const float*)d_in[0];
    const float* ke = (const float*)d_in[1];
    const float* va = (const float*)d_in[2];
    float* out = (float*)d_out;
    float* attn = out + (size_t)BATCH * LSEQ * DDIM;

    bf16* wsQ  = (bf16*)d_ws;
    bf16* wsK  = wsQ + (size_t)BATCH * LSEQ * DDIM;
    bf16* wsVt = wsK + (size_t)BATCH * LSEQ * DDIM;

    const int n4 = BATCH * LSEQ * DDIM / 4;  // 2097152 float4 chunks

    convert_kernel<<<2048, 256, 0, stream>>>((const float4*)qu, (bf16x4*)wsQ, n4, RSCALE);
    convert_kernel<<<2048, 256, 0, stream>>>((const float4*)ke, (bf16x4*)wsK, n4, 1.0f);
    transpose_v_kernel<<<dim3(32, 4, 32), 256, 0, stream>>>(va, wsVt);
    attn_kernel<<<dim3(32, 32), 256, 0, stream>>>(wsQ, wsK, wsVt, out, attn);
}